// Round 10
// baseline (594.561 us; speedup 1.0000x reference)
//
#include <hip/hip_runtime.h>
#include <hip/hip_bf16.h>
#include <stdint.h>

// ---------- bf16 helpers (raw ushort representation) ----------
__device__ inline float bf2f(ushort u) {
    union { uint32_t u; float f; } v; v.u = ((uint32_t)u) << 16; return v.f;
}
__device__ inline ushort f2bf(float f) {
    union { float f; uint32_t u; } v; v.f = f;
    uint32_t u = v.u;
    uint32_t r = (u + 0x7fffu + ((u >> 16) & 1u)) >> 16;  // RNE
    return (ushort)r;
}
__device__ inline uint32_t pk2bf(uint32_t flo, uint32_t fhi) {  // two f32 bit-patterns -> packed bf16x2
    uint32_t lo = (flo + 0x7fffu + ((flo >> 16) & 1u)) >> 16;
    uint32_t hi = (fhi + 0x7fffu + ((fhi >> 16) & 1u)) >> 16;
    return lo | (hi << 16);
}

typedef __attribute__((ext_vector_type(8))) short bf16x8;
typedef __attribute__((ext_vector_type(4))) float f32x4;

// async global->LDS, 16B per lane; LDS dest must be wave-uniform base (HW adds lane*16)
__device__ inline void gload_lds16(const ushort* g, ushort* l) {
    __builtin_amdgcn_global_load_lds(
        (const __attribute__((address_space(1))) void*)g,
        (__attribute__((address_space(3))) void*)l, 16, 0, 0);
}

// ---------- weight transpose+cast: W[1024,1024] f32 -> Wt[1024,1024] bf16 ----------
__global__ void transpose1024(const float* __restrict__ Wq, const float* __restrict__ Wk,
                              const float* __restrict__ Wv, const float* __restrict__ Wo,
                              ushort* __restrict__ WqT, ushort* __restrict__ WkT,
                              ushort* __restrict__ WvT, ushort* __restrict__ WoT) {
    const float* in; ushort* out;
    switch (blockIdx.z) {
        case 0: in = Wq; out = WqT; break;
        case 1: in = Wk; out = WkT; break;
        case 2: in = Wv; out = WvT; break;
        default: in = Wo; out = WoT; break;
    }
    __shared__ ushort tile[64][65];
    const int t = threadIdx.x;
    const int c = t & 63, rq = t >> 6;
    const int bx = blockIdx.x * 64, by = blockIdx.y * 64;
#pragma unroll
    for (int i = 0; i < 16; ++i) {
        int r = i * 4 + rq;
        tile[r][c] = f2bf(in[(size_t)(by + r) * 1024 + bx + c]);
    }
    __syncthreads();
#pragma unroll
    for (int i = 0; i < 16; ++i) {
        int r = i * 4 + rq;
        out[(size_t)(bx + r) * 1024 + by + c] = tile[c][r];
    }
}

// ---------- x chunk cast: f32 -> bf16, 8 elems/thread, grid-stride ----------
__global__ __launch_bounds__(256)
void cast_bf16(const float* __restrict__ in, ushort* __restrict__ out, size_t n8) {
    size_t i = (size_t)blockIdx.x * blockDim.x + threadIdx.x;
    const size_t stride = (size_t)gridDim.x * blockDim.x;
    for (; i < n8; i += stride) {
        const uint4 lo = *(const uint4*)&in[i * 8];
        const uint4 hi = *(const uint4*)&in[i * 8 + 4];
        uint4 o;
        o.x = pk2bf(lo.x, lo.y); o.y = pk2bf(lo.z, lo.w);
        o.z = pk2bf(hi.x, hi.y); o.w = pk2bf(hi.z, hi.w);
        *(uint4*)&out[i * 8] = o;
    }
}

// ---------- 256x256 8-phase bf16 GEMM: C[M,N] = A[M,K] @ Bt[N,K]^T ----------
// Structure UNCHANGED since round 8 (control): M/N-split full-line staging, T2
// granule swizzle (0 conflicts measured), counted vmcnt checkpoint at P0,
// setprio, XCD swizzle. Round 10 changes only data placement at the call sites
// (contiguous Oc as the O-GEMM A-operand, lda=1024 instead of 3072).
template <bool C_F32>
__global__ __launch_bounds__(512, 2)
void gemm256(const ushort* __restrict__ A, int lda, const ushort* __restrict__ Bt,
             void* __restrict__ C_, int M, int N, int K) {
    __shared__ __attribute__((aligned(16))) ushort lds[65536];  // 128 KiB
    const int t = threadIdx.x;
    const int lane = t & 63, wave = t >> 6;
    const int wm = wave >> 2, wn = wave & 3;       // 2 x 4 wave grid
    const int quad = lane >> 4, l16 = lane & 15;

    // bijective XCD swizzle (m204) on linear tile id
    const int gx = N >> 8;
    const int nwg = gridDim.x * gridDim.y;
    int wg = blockIdx.y * gridDim.x + blockIdx.x;
    {
        const int q = nwg >> 3, r = nwg & 7;
        const int xcd = wg & 7, loc = wg >> 3;
        wg = (xcd < r ? xcd * (q + 1) : r * (q + 1) + (xcd - r) * q) + loc;
    }
    const int m0 = (wg / gx) << 8, n0 = (wg % gx) << 8;

    const f32x4 zero = {0.f, 0.f, 0.f, 0.f};
    f32x4 acc[8][4];
#pragma unroll
    for (int i = 0; i < 8; ++i)
#pragma unroll
        for (int j = 0; j < 4; ++j) acc[i][j] = zero;

    // stage one 16KB region = [128 rows][64 cols], full-128B-line rows.
    auto STAGE = [&](const ushort* __restrict__ src, int ldb, int rc0, int kcol,
                     int regio, int buf) {
        ushort* l = &lds[buf * 32768 + regio];
#pragma unroll
        for (int j = 0; j < 2; ++j) {
            const int g = j * 512 + t;
            const int r = g >> 3;
            const int cg = (((g & 7) ^ (r & 7)) * 8);
            gload_lds16(&src[(size_t)(rc0 + r) * ldb + kcol + cg],
                        &l[(j * 512 + wave * 64) * 8]);
        }
    };
    // swizzled ds_read offset: region-local row R (0-127), col granule gq (0-7)
    auto LOFF = [&](int R, int gq) { return R * 64 + ((gq ^ (R & 7)) * 8); };

    const int NT = K >> 6;
    const int abase = wm * 8192;                   // Ah(wm)
    const int bbase = 16384 + (wn >> 1) * 8192;    // Bh(wn>>1)
    const int brow = (wn & 1) * 64;                // local row offset inside B-half

    // ---- prologue: stage tile 0 (4 regions), drain, barrier ----
    STAGE(A, lda, m0, 0, 0, 0);
    STAGE(A, lda, m0 + 128, 0, 8192, 0);
    STAGE(Bt, K, n0, 0, 16384, 0);
    STAGE(Bt, K, n0 + 128, 0, 24576, 0);
    asm volatile("s_waitcnt vmcnt(0)" ::: "memory");
    __builtin_amdgcn_s_barrier();

    int cur = 0;
    for (int kt = 0; kt < NT; ++kt) {
        const bool nx = kt + 1 < NT;
        const int kn = (kt + 1) << 6;
        const ushort* la = &lds[cur * 32768 + abase];
        const ushort* lb = &lds[cur * 32768 + bbase];
        bf16x8 af[4], bf[4];

        // ================= P0: checkpoint; ks0, mt 0-3 =================
        if (nx) STAGE(A, lda, m0, kn, 0, cur ^ 1);             // Ah0(next)
        if (kt > 0) {
            if (nx) asm volatile("s_waitcnt vmcnt(2)" ::: "memory");
            else    asm volatile("s_waitcnt vmcnt(0)" ::: "memory");
        }
        __builtin_amdgcn_s_barrier();
#pragma unroll
        for (int i = 0; i < 4; ++i) {
            af[i] = *(const bf16x8*)&la[LOFF(i * 16 + l16, quad)];
            bf[i] = *(const bf16x8*)&lb[LOFF(brow + i * 16 + l16, quad)];
        }
        __builtin_amdgcn_s_setprio(1);
#pragma unroll
        for (int i = 0; i < 4; ++i)
#pragma unroll
            for (int n = 0; n < 4; ++n)
                acc[i][n] = __builtin_amdgcn_mfma_f32_16x16x32_bf16(af[i], bf[n], acc[i][n], 0, 0, 0);
        __builtin_amdgcn_s_setprio(0);
        __builtin_amdgcn_s_barrier();

        // ================= P1: ks0, mt 4-7 =================
#pragma unroll
        for (int i = 0; i < 4; ++i)
            af[i] = *(const bf16x8*)&la[LOFF((i + 4) * 16 + l16, quad)];
        if (nx) STAGE(A, lda, m0 + 128, kn, 8192, cur ^ 1);    // Ah1(next)
        __builtin_amdgcn_s_barrier();
        __builtin_amdgcn_s_setprio(1);
#pragma unroll
        for (int i = 0; i < 4; ++i)
#pragma unroll
            for (int n = 0; n < 4; ++n)
                acc[i + 4][n] = __builtin_amdgcn_mfma_f32_16x16x32_bf16(af[i], bf[n], acc[i + 4][n], 0, 0, 0);
        __builtin_amdgcn_s_setprio(0);
        __builtin_amdgcn_s_barrier();

        // ================= P2: ks1, mt 0-3 =================
#pragma unroll
        for (int i = 0; i < 4; ++i) {
            af[i] = *(const bf16x8*)&la[LOFF(i * 16 + l16, 4 + quad)];
            bf[i] = *(const bf16x8*)&lb[LOFF(brow + i * 16 + l16, 4 + quad)];
        }
        if (nx) STAGE(Bt, K, n0, kn, 16384, cur ^ 1);          // Bh0(next)
        __builtin_amdgcn_s_barrier();
        __builtin_amdgcn_s_setprio(1);
#pragma unroll
        for (int i = 0; i < 4; ++i)
#pragma unroll
            for (int n = 0; n < 4; ++n)
                acc[i][n] = __builtin_amdgcn_mfma_f32_16x16x32_bf16(af[i], bf[n], acc[i][n], 0, 0, 0);
        __builtin_amdgcn_s_setprio(0);
        __builtin_amdgcn_s_barrier();

        // ================= P3: ks1, mt 4-7 =================
#pragma unroll
        for (int i = 0; i < 4; ++i)
            af[i] = *(const bf16x8*)&la[LOFF((i + 4) * 16 + l16, 4 + quad)];
        if (nx) STAGE(Bt, K, n0 + 128, kn, 24576, cur ^ 1);    // Bh1(next)
        __builtin_amdgcn_s_barrier();
        __builtin_amdgcn_s_setprio(1);
#pragma unroll
        for (int i = 0; i < 4; ++i)
#pragma unroll
            for (int n = 0; n < 4; ++n)
                acc[i + 4][n] = __builtin_amdgcn_mfma_f32_16x16x32_bf16(af[i], bf[n], acc[i + 4][n], 0, 0, 0);
        __builtin_amdgcn_s_setprio(0);
        __builtin_amdgcn_s_barrier();

        cur ^= 1;
    }

    // ---- epilogue: C/D layout col = lane&15, row = quad*4 + reg ----
#pragma unroll
    for (int mt = 0; mt < 8; ++mt)
#pragma unroll
        for (int nt = 0; nt < 4; ++nt)
#pragma unroll
            for (int r4 = 0; r4 < 4; ++r4) {
                const int row = m0 + wm * 128 + mt * 16 + quad * 4 + r4;
                const int col = n0 + wn * 64 + nt * 16 + l16;
                if (C_F32) ((float*)C_)[(size_t)row * N + col] = acc[mt][nt][r4];
                else       ((ushort*)C_)[(size_t)row * N + col] = f2bf(acc[mt][nt][r4]);
            }
}

// ---------- MFMA attention (fused-QKV input, contiguous O output) ----------
// Block = (b,h) 64x64 tile, 4 waves, wave w owns q rows [16w,16w+16).
// QKV: [tokens, 3072] bf16 (Q 0..1023, K 1024..2047, V 2048..3071).
// O is written to a CONTIGUOUS Oc[tokens][1024] (round 10): gives the O-GEMM
// an lda=1024 dense A-operand (was lda=3072 in-place — the 2.2x per-tile
// anomaly hypothesis) and makes attn's own O-stores land in dense 2KB rows.
// V tile staged through LDS with transposed swizzled write (conflict-free).
__global__ __launch_bounds__(256)
void attn_mfma(const ushort* __restrict__ QKV, ushort* __restrict__ Oc,
               const float* __restrict__ bias, int CROWS) {
    const int t = threadIdx.x;
    const int lane = t & 63, wave = t >> 6;
    const int quad = lane >> 4, l16 = lane & 15;
    const int b = blockIdx.x >> 4, h = blockIdx.x & 15;
    const int SQK = 3072;
    const size_t qbase = (size_t)b * 64 * SQK + (size_t)h * 64;
    const size_t kbase = qbase + 1024;

    __shared__ __attribute__((aligned(16))) ushort Pl[4 * 16 * 72];  // per-wave P[16][64]
    __shared__ __attribute__((aligned(16))) ushort Vt[64 * 72];      // V^T[d][tok], swizzled

    // ---- issue V tile loads early (latency hidden under QK^T/softmax) ----
    bf16x8 vstage[2];
#pragma unroll
    for (int i = 0; i < 2; ++i) {
        const int s = i * 256 + t;
        const int tok = s >> 3, g = s & 7;
        vstage[i] = *(const bf16x8*)&QKV[(size_t)(b * 64 + tok) * SQK + 2048 + h * 64 + g * 8];
    }

    // ---- Q fragments: row=l16 (q within band), k(d)=ks*32+quad*8 ----
    bf16x8 qf[2];
#pragma unroll
    for (int ks = 0; ks < 2; ++ks)
        qf[ks] = *(const bf16x8*)&QKV[qbase + (size_t)(wave * 16 + l16) * SQK + ks * 32 + quad * 8];

    // ---- S = Q K^T (contraction over d=64): M=16 q, N=64 kt ----
    const f32x4 zero = {0.f, 0.f, 0.f, 0.f};
    f32x4 s[4];
#pragma unroll
    for (int nt = 0; nt < 4; ++nt) s[nt] = zero;
#pragma unroll
    for (int nt = 0; nt < 4; ++nt)
#pragma unroll
        for (int ks = 0; ks < 2; ++ks) {
            bf16x8 kf = *(const bf16x8*)&QKV[kbase + (size_t)(nt * 16 + l16) * SQK + ks * 32 + quad * 8];
            s[nt] = __builtin_amdgcn_mfma_f32_16x16x32_bf16(qf[ks], kf, s[nt], 0, 0, 0);
        }

    // ---- scale + bias; acc layout: row q = quad*4+r4 (+wave band), col kt = nt*16+l16 ----
    const int q0 = wave * 16 + quad * 4;
    float p[4][4];  // [nt][r4]
#pragma unroll
    for (int nt = 0; nt < 4; ++nt)
#pragma unroll
        for (int r4 = 0; r4 < 4; ++r4)
            p[nt][r4] = s[nt][r4] * 0.125f +
                        bias[(size_t)(h * 64 + q0 + r4) * 64 + nt * 16 + l16];

    // ---- row softmax: reduce over nt then across the 16 lanes of the quad ----
    float rinv[4];
#pragma unroll
    for (int r4 = 0; r4 < 4; ++r4) {
        float m = fmaxf(fmaxf(p[0][r4], p[1][r4]), fmaxf(p[2][r4], p[3][r4]));
        m = fmaxf(m, __shfl_xor(m, 1));
        m = fmaxf(m, __shfl_xor(m, 2));
        m = fmaxf(m, __shfl_xor(m, 4));
        m = fmaxf(m, __shfl_xor(m, 8));
#pragma unroll
        for (int nt = 0; nt < 4; ++nt) p[nt][r4] = __expf(p[nt][r4] - m);
        float sum = p[0][r4] + p[1][r4] + p[2][r4] + p[3][r4];
        sum += __shfl_xor(sum, 1);
        sum += __shfl_xor(sum, 2);
        sum += __shfl_xor(sum, 4);
        sum += __shfl_xor(sum, 8);
        rinv[r4] = 1.f / sum;
    }

    // ---- repack P to bf16 in LDS for the PV A-operand ----
#pragma unroll
    for (int nt = 0; nt < 4; ++nt)
#pragma unroll
        for (int r4 = 0; r4 < 4; ++r4)
            Pl[(wave * 16 + quad * 4 + r4) * 72 + nt * 16 + l16] = f2bf(p[nt][r4]);

    // ---- transposed V write: (tok, d=g*8+j) -> Vt[d][tok] swizzled ----
#pragma unroll
    for (int i = 0; i < 2; ++i) {
        const int s = i * 256 + t;
        const int tok = s >> 3, g = s & 7;
#pragma unroll
        for (int j = 0; j < 8; ++j) {
            const int d = g * 8 + j;
            Vt[d * 72 + (((tok >> 3) ^ ((d >> 3) & 7)) << 3) + (tok & 7)] =
                (ushort)vstage[i][j];
        }
    }
    __syncthreads();

    // ---- O = P V (contraction over kt=64): M=16 q, N=64 d ----
    bf16x8 pa[2];
#pragma unroll
    for (int ks = 0; ks < 2; ++ks)
        pa[ks] = *(const bf16x8*)&Pl[(wave * 16 + l16) * 72 + ks * 32 + quad * 8];
    f32x4 o[4];
#pragma unroll
    for (int nt = 0; nt < 4; ++nt) o[nt] = zero;
#pragma unroll
    for (int nt = 0; nt < 4; ++nt)
#pragma unroll
        for (int ks = 0; ks < 2; ++ks) {
            const int d = nt * 16 + l16;
            bf16x8 vf = *(const bf16x8*)&Vt[d * 72 + (((ks * 4 + quad) ^ ((d >> 3) & 7)) << 3)];
            o[nt] = __builtin_amdgcn_mfma_f32_16x16x32_bf16(pa[ks], vf, o[nt], 0, 0, 0);
        }

    // ---- write O (deferred 1/l scaling) to contiguous Oc[tok][1024] ----
#pragma unroll
    for (int nt = 0; nt < 4; ++nt)
#pragma unroll
        for (int r4 = 0; r4 < 4; ++r4)
            Oc[(size_t)(b * 64 + q0 + r4) * 1024 + h * 64 + nt * 16 + l16] =
                f2bf(o[nt][r4] * rinv[r4]);
}

extern "C" void kernel_launch(void* const* d_in, const int* in_sizes, int n_in,
                              void* d_out, int out_size, void* d_ws, size_t ws_size,
                              hipStream_t stream) {
    const float* x    = (const float*)d_in[0];   // [512,64,1024] f32
    const float* bias = (const float*)d_in[1];   // [1,16,64,64]  f32
    const float* Wq   = (const float*)d_in[2];
    const float* Wk   = (const float*)d_in[3];
    const float* Wv   = (const float*)d_in[4];
    const float* Wo   = (const float*)d_in[5];
    float* out = (float*)d_out;                  // [512,64,1024] f32

    const size_t D = 1024;
    const size_t WB = 4 * D * D * 2;             // 8.39 MB bf16 weights

    // per chunk after weights: QKVc CROWS*3072*2 + Oc CROWS*1024*2 bytes
    auto need = [&](size_t cb) { return WB + cb * 64 * (6144 + 2048); };
    int CHUNK_B = 64;                            // last-resort tier (41.9 MB)
    if      (ws_size >= need(512)) CHUNK_B = 512;   // 276.8 MB
    else if (ws_size >= need(256)) CHUNK_B = 256;   // 142.6 MB (engaged if ws==~210MB)
    else if (ws_size >= need(128)) CHUNK_B = 128;   //  75.5 MB
    const int NCHUNK = 512 / CHUNK_B;
    const size_t CROWS = (size_t)CHUNK_B * 64;
    const size_t CELEM = CROWS * D;

    // ws layout: WqT|WkT|WvT (contiguous => fused [3072][1024] B-matrix) | WoT | QKVc | Oc
    ushort* WqT  = (ushort*)d_ws;
    ushort* WkT  = WqT + D * D;
    ushort* WvT  = WkT + D * D;
    ushort* WoT  = WvT + D * D;
    ushort* QKVc = WoT + D * D;                  // [CROWS][3072] bf16
    ushort* Oc   = QKVc + CROWS * 3072;          // [CROWS][1024] bf16 (contiguous O)

    transpose1024<<<dim3(16, 16, 4), 256, 0, stream>>>(Wq, Wk, Wv, Wo, WqT, WkT, WvT, WoT);

    for (int c = 0; c < NCHUNK; ++c) {
        const float* xc = x + (size_t)c * CELEM;
        float* outc = out + (size_t)c * CELEM;
        ushort* Xc = (ushort*)outc;              // scratch: consumed before final GEMM writes
        cast_bf16<<<2048, 256, 0, stream>>>(xc, Xc, CELEM / 8);
        // fused Q|K|V projection: C[t][0..3071]
        gemm256<false><<<dim3(12, CROWS / 256), 512, 0, stream>>>(
            Xc, 1024, WqT, QKVc, (int)CROWS, 3072, 1024);
        // attention: reads QKVc, writes contiguous Oc
        attn_mfma<<<CHUNK_B * 16, 256, 0, stream>>>(QKVc, Oc, bias, (int)CROWS);
        // output projection: A = Oc (lda=1024, dense)
        gemm256<true><<<dim3(4, CROWS / 256), 512, 0, stream>>>(
            Oc, 1024, WoT, outc, (int)CROWS, 1024, 1024);
    }
}